// Round 8
// baseline (201.388 us; speedup 1.0000x reference)
//
#include <hip/hip_runtime.h>
#include <hip/hip_fp16.h>

#define N_NODES 100000
#define N_EDGES 1600000
#define D 64

// ---------- counting-sort CSR parameters ----------
#define NB 391            // buckets = src>>8 (256 nodes each)
#define BLKA 391          // hist/scatter columns (blocks)
#define EPB 4096          // edges per column (391*4096 = 1,601,536 >= 1.6M)
#define GST 400           // padded ghist column stride (ints)

// ---- ws layout (4-byte units), end = 5,056,864 ints = 20,227,456 B (ws >= 20,400,640) ----
#define WS_GHIST   0                 // [391*400] col-major per-(col,bucket) counts (raw)
#define WS_G       156416            // [392] bucket starts (scanned), written by scatter blk 0
#define WS_ROWPTR  156832            // [100,032] row_ptr (+pad)
#define WS_PAIRSU  256864            // uint[1,600,000] packed CSR: (dst<<15)|(fp16(val)>>1)
#define WS_XH      1856864           // fp16 x [100,000*64] = 3,200,000 ints (16B-aligned)
// tpairs (int2[1.6M], bucket-sorted, (src&255)<<17|dst) lives in the rep
// region of d_out: fully consumed by k_build before k_gather writes rep.

// ---------------- pass A: per-(column,bucket) histogram + x->fp16 ----------------
// ghist written COLUMN-MAJOR (ghist[blk*GST + j], coalesced) so k_scatter's
// prologue can recompute the scan itself (R7 post-mortem: kills both scan
// kernels + their launch gaps). fp16 cvt fused (x ~ N(0,1): rel err 2^-11).
__global__ __launch_bounds__(512) void k_hist_cvt(
    const int* __restrict__ esrc, const float* __restrict__ x,
    int* __restrict__ ghist, uint2* __restrict__ xh2)
{
    __shared__ int h[NB];
    int t = threadIdx.x, blk = blockIdx.x;
    if (t < NB) h[t] = 0;
    __syncthreads();
    int base = blk * EPB;
    #pragma unroll
    for (int i = 0; i < 2; ++i) {
        int e0 = base + i * 2048 + t * 4;
        if (e0 < N_EDGES) {                  // N_EDGES%4==0 -> whole int4 valid
            int4 s4 = *(const int4*)(esrc + e0);
            atomicAdd(&h[s4.x >> 8], 1);
            atomicAdd(&h[s4.y >> 8], 1);
            atomicAdd(&h[s4.z >> 8], 1);
            atomicAdd(&h[s4.w >> 8], 1);
        }
    }
    // x -> fp16 slice (independent of hist; overlaps the LDS atomics)
    {
        const float4* x4 = (const float4*)x;
        #pragma unroll
        for (int i = 0; i < 8; ++i) {
            int f = blk * 4096 + i * 512 + t;   // float4 index, 1.6M total
            if (f < N_NODES * (D / 4)) {
                float4 v = x4[f];
                uint2 o;
                o.x = (unsigned int)__half_as_ushort(__float2half_rn(v.x)) |
                      ((unsigned int)__half_as_ushort(__float2half_rn(v.y)) << 16);
                o.y = (unsigned int)__half_as_ushort(__float2half_rn(v.z)) |
                      ((unsigned int)__half_as_ushort(__float2half_rn(v.w)) << 16);
                xh2[f] = o;
            }
        }
    }
    __syncthreads();
    if (t < NB) ghist[blk * GST + t] = h[t];
}

// ---------------- pass A scatter (scan fused in prologue) ----------------
// Prologue: thread t owns bucket j=t; streams all 391 columns of ghist
// (coalesced across threads, 800KB L2-resident) -> tot[j] and P[j] (cols <
// own blk). 8-wave shfl scan of tot -> bucket base G[j]; base[j] = G+P.
// Block 0 publishes G[] for k_build. Body: LDS cursor atomic-returns;
// packed record ((src&255)<<17 | dst, val); dst < 2^17.
__global__ __launch_bounds__(512) void k_scatter(
    const int* __restrict__ esrc, const int* __restrict__ edst,
    const float* __restrict__ eval_, const int* __restrict__ ghist,
    int* __restrict__ G, int2* __restrict__ tpairs)
{
    __shared__ int base[NB];
    __shared__ int wsum[8];
    int t = threadIdx.x, blk = blockIdx.x;
    int lane = t & 63, wid = t >> 6;

    int tot = 0, P = 0;
    if (t < NB) {
        for (int c = 0; c < BLKA; ++c) {
            int v = ghist[c * GST + t];
            tot += v;
            if (c < blk) P += v;
        }
    }
    // exclusive scan of tot across 512 threads (391 active)
    int s = tot;
    #pragma unroll
    for (int off = 1; off < 64; off <<= 1) {
        int y = __shfl_up(s, off, 64);
        if (lane >= off) s += y;
    }
    if (lane == 63) wsum[wid] = s;
    __syncthreads();
    if (t == 0) {
        int r = 0;
        #pragma unroll
        for (int k = 0; k < 8; ++k) { int v = wsum[k]; wsum[k] = r; r += v; }
    }
    __syncthreads();
    int Gv = wsum[wid] + s - tot;    // exclusive bucket start
    if (t < NB) {
        base[t] = Gv + P;
        if (blk == 0) {
            G[t] = Gv;
            if (t == NB - 1) G[NB] = Gv + tot;
        }
    }
    __syncthreads();

    int eb = blk * EPB;
    #pragma unroll
    for (int i = 0; i < 2; ++i) {
        int e0 = eb + i * 2048 + t * 4;
        if (e0 < N_EDGES) {
            int4 s4 = *(const int4*)(esrc + e0);
            int4 d4 = *(const int4*)(edst + e0);
            float4 v4 = *(const float4*)(eval_ + e0);
            int p0 = atomicAdd(&base[s4.x >> 8], 1);
            int p1 = atomicAdd(&base[s4.y >> 8], 1);
            int p2 = atomicAdd(&base[s4.z >> 8], 1);
            int p3 = atomicAdd(&base[s4.w >> 8], 1);
            tpairs[p0] = make_int2(((s4.x & 255) << 17) | d4.x, __float_as_int(v4.x));
            tpairs[p1] = make_int2(((s4.y & 255) << 17) | d4.y, __float_as_int(v4.y));
            tpairs[p2] = make_int2(((s4.z & 255) << 17) | d4.z, __float_as_int(v4.z));
            tpairs[p3] = make_int2(((s4.w & 255) << 17) | d4.w, __float_as_int(v4.w));
        }
    }
}

// ---------------- pass B: per-bucket CSR finalize ----------------
// One 256-thr block per 256-node bucket (~4.1K edges): LDS 256-bin hist+scan
// -> row_ptr + ranks; output packed to 4B/edge: (dst<<15) | (fp16(val)>>1).
// Bucket bounds read directly from G (published by k_scatter block 0).
__global__ __launch_bounds__(256) void k_build(
    const int2* __restrict__ tpairs, const int* __restrict__ G,
    int* __restrict__ row_ptr, unsigned int* __restrict__ pairsu)
{
    __shared__ int hist[256], cursor[256], wsum4[4];
    int b = blockIdx.x, t = threadIdx.x;
    int s_begin = G[b];
    int s_end   = G[b + 1];
    hist[t] = 0;
    __syncthreads();
    #pragma unroll 4
    for (int pos = s_begin + t; pos < s_end; pos += 256)
        atomicAdd(&hist[(tpairs[pos].x >> 17) & 255], 1);
    __syncthreads();
    // exclusive scan of 256 bins
    int lane = t & 63, wid = t >> 6;
    int v = hist[t], s = v;
    #pragma unroll
    for (int off = 1; off < 64; off <<= 1) {
        int y = __shfl_up(s, off, 64);
        if (lane >= off) s += y;
    }
    if (lane == 63) wsum4[wid] = s;
    __syncthreads();
    if (t == 0) {
        int r = 0;
        #pragma unroll
        for (int k = 0; k < 4; ++k) { int w = wsum4[k]; wsum4[k] = r; r += w; }
    }
    __syncthreads();
    int excl = wsum4[wid] + s - v;
    cursor[t] = excl;
    int node = (b << 8) + t;
    if (node <= N_NODES) row_ptr[node] = s_begin + excl;
    __syncthreads();
    #pragma unroll 4
    for (int pos = s_begin + t; pos < s_end; pos += 256) {
        int2 pv = tpairs[pos];
        int k = (pv.x >> 17) & 255;
        int p = atomicAdd(&cursor[k], 1);
        unsigned int dst = (unsigned int)pv.x & 0x1FFFFu;
        unsigned int hb = (unsigned int)__half_as_ushort(
            __float2half_rn(__int_as_float(pv.y)));
        pairsu[s_begin + p] = (dst << 15) | (hb >> 1);
    }
}

// ---------------- aggregation: rep = agg + eps*x ----------------
// R7 post-mortem: fp16 halved bytes but also halved in-flight bytes (rate
// 3.37->2.77 TB/s). New layout: 8 edges x 8 lanes/wave, lane loads uint4
// (16B = dwordx4) -> 4KB in flight/wave again, 8 VMEM instrs per 32-edge
// step. eps*x now computed from fp16 x too (err ~eps*x*2^-11 ~ 0.002):
// drops the 25.6MB fp32-x read entirely.
#define GATHER_BLOCKS 2048

__global__ __launch_bounds__(256) void k_gather(
    const uint4* __restrict__ xh4, const int* __restrict__ row_ptr,
    const unsigned int* __restrict__ pairsu, const float* __restrict__ epsilon,
    float* __restrict__ rep)
{
    int w = (blockIdx.x * 256 + threadIdx.x) >> 6;   // global wave id
    int nw = gridDim.x * 4;                          // 8192
    int lane = threadIdx.x & 63;
    int sub = lane >> 3;                             // edge slot 0..7
    int h8 = lane & 7;                               // 16B chunk idx (8 per row)
    float eps = epsilon[0];

    int r0 = (int)((long long)w * N_NODES / nw);
    int r1 = (int)((long long)(w + 1) * N_NODES / nw);

    for (int row = r0; row < r1; ++row) {
        int start = __builtin_amdgcn_readfirstlane(row_ptr[row]);
        int end   = __builtin_amdgcn_readfirstlane(row_ptr[row + 1]);
        float4 accA = make_float4(0.f, 0.f, 0.f, 0.f);
        float4 accB = make_float4(0.f, 0.f, 0.f, 0.f);
        for (int j = start; j < end; j += 32) {
            unsigned int pk[4]; uint4 a[4];
            #pragma unroll
            for (int u = 0; u < 4; ++u) {
                int e = j + u * 8 + sub;
                pk[u] = (e < end) ? pairsu[e] : 0u;   // 0 -> dst 0, val 0
            }
            #pragma unroll
            for (int u = 0; u < 4; ++u)
                a[u] = xh4[(size_t)(pk[u] >> 15) * 8 + h8];
            #pragma unroll
            for (int u = 0; u < 4; ++u) {
                unsigned short hb = (unsigned short)((pk[u] & 0x7FFFu) << 1);
                float vv = __half2float(__ushort_as_half(hb));
                float2 f0 = __half22float2(*reinterpret_cast<const __half2*>(&a[u].x));
                float2 f1 = __half22float2(*reinterpret_cast<const __half2*>(&a[u].y));
                float2 f2 = __half22float2(*reinterpret_cast<const __half2*>(&a[u].z));
                float2 f3 = __half22float2(*reinterpret_cast<const __half2*>(&a[u].w));
                accA.x += vv * f0.x; accA.y += vv * f0.y;
                accA.z += vv * f1.x; accA.w += vv * f1.y;
                accB.x += vv * f2.x; accB.y += vv * f2.y;
                accB.z += vv * f3.x; accB.w += vv * f3.y;
            }
        }
        // reduce the 8 edge-slots (lane bits 3,4,5)
        #pragma unroll
        for (int off = 8; off <= 32; off <<= 1) {
            accA.x += __shfl_xor(accA.x, off, 64);
            accA.y += __shfl_xor(accA.y, off, 64);
            accA.z += __shfl_xor(accA.z, off, 64);
            accA.w += __shfl_xor(accA.w, off, 64);
            accB.x += __shfl_xor(accB.x, off, 64);
            accB.y += __shfl_xor(accB.y, off, 64);
            accB.z += __shfl_xor(accB.z, off, 64);
            accB.w += __shfl_xor(accB.w, off, 64);
        }
        if (lane < 8) {                              // sub==0, h8==lane
            uint4 xr = xh4[(size_t)row * 8 + lane];
            float2 x0 = __half22float2(*reinterpret_cast<const __half2*>(&xr.x));
            float2 x1 = __half22float2(*reinterpret_cast<const __half2*>(&xr.y));
            float2 x2 = __half22float2(*reinterpret_cast<const __half2*>(&xr.z));
            float2 x3 = __half22float2(*reinterpret_cast<const __half2*>(&xr.w));
            float4* r4 = (float4*)rep;
            r4[(size_t)row * 16 + lane * 2] =
                make_float4(accA.x + eps * x0.x, accA.y + eps * x0.y,
                            accA.z + eps * x1.x, accA.w + eps * x1.y);
            r4[(size_t)row * 16 + lane * 2 + 1] =
                make_float4(accB.x + eps * x2.x, accB.y + eps * x2.y,
                            accB.z + eps * x3.x, accB.w + eps * x3.y);
        }
    }
}

// ---------------- out = rep @ W + bias ----------------
#define GEMM_TM 64
__global__ __launch_bounds__(256) void k_gemm(
    const float* __restrict__ rep, const float* __restrict__ weight,
    const float* __restrict__ bias, float* __restrict__ out)
{
    __shared__ float rep_s[GEMM_TM * 68];
    __shared__ float Ws[D * D];
    int t = threadIdx.x;
    {
        const float4* w4 = (const float4*)weight;
        float4* s4 = (float4*)Ws;
        #pragma unroll
        for (int i = 0; i < (D * D / 4) / 256; ++i)
            s4[t + i * 256] = w4[t + i * 256];
    }
    int row0 = blockIdx.x * GEMM_TM;
    {
        const float4* r4 = (const float4*)rep;
        #pragma unroll
        for (int i = 0; i < 4; ++i) {
            int f = t + i * 256;
            int rr = f >> 4, kk4 = f & 15;
            float4 v = (row0 + rr < N_NODES) ? r4[(size_t)(row0 + rr) * 16 + kk4]
                                             : make_float4(0.f, 0.f, 0.f, 0.f);
            rep_s[rr * 68 + kk4 * 4 + 0] = v.x;
            rep_s[rr * 68 + kk4 * 4 + 1] = v.y;
            rep_s[rr * 68 + kk4 * 4 + 2] = v.z;
            rep_s[rr * 68 + kk4 * 4 + 3] = v.w;
        }
    }
    __syncthreads();

    int tx = t & 15, ty = t >> 4;
    float4 b4 = ((const float4*)bias)[tx];
    float acc[4][4];
    #pragma unroll
    for (int i = 0; i < 4; ++i) {
        acc[i][0] = b4.x; acc[i][1] = b4.y; acc[i][2] = b4.z; acc[i][3] = b4.w;
    }
    #pragma unroll 4
    for (int k4 = 0; k4 < 16; ++k4) {
        float4 rv[4];
        #pragma unroll
        for (int i = 0; i < 4; ++i)
            rv[i] = *(const float4*)&rep_s[(ty * 4 + i) * 68 + k4 * 4];
        #pragma unroll
        for (int kk = 0; kk < 4; ++kk) {
            float4 wv = *(const float4*)&Ws[(k4 * 4 + kk) * D + tx * 4];
            #pragma unroll
            for (int i = 0; i < 4; ++i) {
                float r = ((const float*)&rv[i])[kk];
                acc[i][0] += r * wv.x;
                acc[i][1] += r * wv.y;
                acc[i][2] += r * wv.z;
                acc[i][3] += r * wv.w;
            }
        }
    }
    #pragma unroll
    for (int i = 0; i < 4; ++i) {
        int row = row0 + ty * 4 + i;
        if (row < N_NODES)
            *(float4*)&out[(size_t)row * D + tx * 4] =
                make_float4(acc[i][0], acc[i][1], acc[i][2], acc[i][3]);
    }
}

extern "C" void kernel_launch(void* const* d_in, const int* in_sizes, int n_in,
                              void* d_out, int out_size, void* d_ws, size_t ws_size,
                              hipStream_t stream) {
    const float* x    = (const float*)d_in[0];
    const int*   esrc = (const int*)  d_in[1];
    const int*   edst = (const int*)  d_in[2];
    const float* ev   = (const float*)d_in[3];
    const float* w    = (const float*)d_in[4];
    const float* eps  = (const float*)d_in[5];
    const float* bias = (const float*)d_in[6];

    float* out = (float*)d_out;
    float* rep = out + (size_t)N_NODES * D;

    int* ws       = (int*)d_ws;
    int* ghist    = ws + WS_GHIST;
    int* G        = ws + WS_G;
    int* row_ptr  = ws + WS_ROWPTR;
    unsigned int* pairsu = (unsigned int*)(ws + WS_PAIRSU);
    uint2* xh2    = (uint2*)(ws + WS_XH);
    uint4* xh4    = (uint4*)(ws + WS_XH);
    int2* tpairs  = (int2*)rep;   // consumed by k_build before k_gather writes rep

    k_hist_cvt<<<BLKA, 512, 0, stream>>>(esrc, x, ghist, xh2);
    k_scatter<<<BLKA, 512, 0, stream>>>(esrc, edst, ev, ghist, G, tpairs);
    k_build<<<NB, 256, 0, stream>>>(tpairs, G, row_ptr, pairsu);
    k_gather<<<GATHER_BLOCKS, 256, 0, stream>>>(xh4, row_ptr, pairsu, eps, rep);
    k_gemm<<<(N_NODES + GEMM_TM - 1) / GEMM_TM, 256, 0, stream>>>(rep, w, bias, out);
}

// Round 9
// 199.383 us; speedup vs baseline: 1.0101x; 1.0101x over previous
//
#include <hip/hip_runtime.h>
#include <hip/hip_fp16.h>

#define N_NODES 100000
#define N_EDGES 1600000
#define D 64

// ---------- counting-sort CSR parameters ----------
#define NB 391            // buckets = src>>8 (256 nodes each)
#define BLKA 391          // hist/scatter columns (blocks)
#define EPB 4096          // edges per column (391*4096 = 1,601,536 >= 1.6M)
#define GST 400           // padded ghist column stride (ints)

// ---- ws layout (4-byte units), end = 5,056,864 ints = 20,227,456 B (ws >= 20,400,640) ----
#define WS_GHIST   0                 // [391*400] col-major per-(col,bucket) counts (raw)
#define WS_G       156416            // [392] bucket starts (scanned), written by scatter blk 0
#define WS_ROWPTR  156832            // [100,032] row_ptr (+pad)
#define WS_PAIRSU  256864            // uint[1,600,000] packed CSR: (dst<<15)|(fp16(val)>>1)
#define WS_XH      1856864           // fp16 x [100,000*64] = 3,200,000 ints (16B-aligned)
// tpairs (int2[1.6M], bucket-sorted, (src&255)<<17|dst) lives in the rep
// region of d_out: fully consumed by k_build before k_gather writes rep.

// ---------------- pass A: per-(column,bucket) histogram + x->fp16 ----------------
// ghist written COLUMN-MAJOR (ghist[blk*GST + j], coalesced) so k_scatter's
// prologue recomputes the scan itself. fp16 cvt fused (x ~ N(0,1): rel err 2^-11).
__global__ __launch_bounds__(512) void k_hist_cvt(
    const int* __restrict__ esrc, const float* __restrict__ x,
    int* __restrict__ ghist, uint2* __restrict__ xh2)
{
    __shared__ int h[NB];
    int t = threadIdx.x, blk = blockIdx.x;
    if (t < NB) h[t] = 0;
    __syncthreads();
    int base = blk * EPB;
    #pragma unroll
    for (int i = 0; i < 2; ++i) {
        int e0 = base + i * 2048 + t * 4;
        if (e0 < N_EDGES) {                  // N_EDGES%4==0 -> whole int4 valid
            int4 s4 = *(const int4*)(esrc + e0);
            atomicAdd(&h[s4.x >> 8], 1);
            atomicAdd(&h[s4.y >> 8], 1);
            atomicAdd(&h[s4.z >> 8], 1);
            atomicAdd(&h[s4.w >> 8], 1);
        }
    }
    // x -> fp16 slice (independent of hist; overlaps the LDS atomics)
    {
        const float4* x4 = (const float4*)x;
        #pragma unroll
        for (int i = 0; i < 8; ++i) {
            int f = blk * 4096 + i * 512 + t;   // float4 index, 1.6M total
            if (f < N_NODES * (D / 4)) {
                float4 v = x4[f];
                uint2 o;
                o.x = (unsigned int)__half_as_ushort(__float2half_rn(v.x)) |
                      ((unsigned int)__half_as_ushort(__float2half_rn(v.y)) << 16);
                o.y = (unsigned int)__half_as_ushort(__float2half_rn(v.z)) |
                      ((unsigned int)__half_as_ushort(__float2half_rn(v.w)) << 16);
                xh2[f] = o;
            }
        }
    }
    __syncthreads();
    if (t < NB) ghist[blk * GST + t] = h[t];
}

// ---------------- pass A scatter (scan fused in prologue) ----------------
// R8 post-mortem: the prologue's 391-column reduction ran at ~2 loads in
// flight (~22us). Per-thread work (300 loads) is irreducible — the fix is
// MLP: batch 16 independent loads into registers per iteration (~25 batches
// x ~280cy ≈ 3-4us) + branch-free prefix accumulate.
__global__ __launch_bounds__(512) void k_scatter(
    const int* __restrict__ esrc, const int* __restrict__ edst,
    const float* __restrict__ eval_, const int* __restrict__ ghist,
    int* __restrict__ G, int2* __restrict__ tpairs)
{
    __shared__ int base[NB];
    __shared__ int wsum[8];
    int t = threadIdx.x, blk = blockIdx.x;
    int lane = t & 63, wid = t >> 6;

    int tot = 0, P = 0;
    if (t < NB) {
        int c = 0;
        for (; c + 16 <= BLKA; c += 16) {     // 24 full batches
            int v[16];
            #pragma unroll
            for (int k = 0; k < 16; ++k) v[k] = ghist[(c + k) * GST + t];
            #pragma unroll
            for (int k = 0; k < 16; ++k) {
                tot += v[k];
                P += ((c + k) < blk) ? v[k] : 0;
            }
        }
        for (; c < BLKA; ++c) {               // 7-iter tail
            int v = ghist[c * GST + t];
            tot += v;
            P += (c < blk) ? v : 0;
        }
    }
    // exclusive scan of tot across 512 threads (391 active)
    int s = tot;
    #pragma unroll
    for (int off = 1; off < 64; off <<= 1) {
        int y = __shfl_up(s, off, 64);
        if (lane >= off) s += y;
    }
    if (lane == 63) wsum[wid] = s;
    __syncthreads();
    if (t == 0) {
        int r = 0;
        #pragma unroll
        for (int k = 0; k < 8; ++k) { int v = wsum[k]; wsum[k] = r; r += v; }
    }
    __syncthreads();
    int Gv = wsum[wid] + s - tot;    // exclusive bucket start
    if (t < NB) {
        base[t] = Gv + P;
        if (blk == 0) {
            G[t] = Gv;
            if (t == NB - 1) G[NB] = Gv + tot;
        }
    }
    __syncthreads();

    int eb = blk * EPB;
    #pragma unroll
    for (int i = 0; i < 2; ++i) {
        int e0 = eb + i * 2048 + t * 4;
        if (e0 < N_EDGES) {
            int4 s4 = *(const int4*)(esrc + e0);
            int4 d4 = *(const int4*)(edst + e0);
            float4 v4 = *(const float4*)(eval_ + e0);
            int p0 = atomicAdd(&base[s4.x >> 8], 1);
            int p1 = atomicAdd(&base[s4.y >> 8], 1);
            int p2 = atomicAdd(&base[s4.z >> 8], 1);
            int p3 = atomicAdd(&base[s4.w >> 8], 1);
            tpairs[p0] = make_int2(((s4.x & 255) << 17) | d4.x, __float_as_int(v4.x));
            tpairs[p1] = make_int2(((s4.y & 255) << 17) | d4.y, __float_as_int(v4.y));
            tpairs[p2] = make_int2(((s4.z & 255) << 17) | d4.z, __float_as_int(v4.z));
            tpairs[p3] = make_int2(((s4.w & 255) << 17) | d4.w, __float_as_int(v4.w));
        }
    }
}

// ---------------- pass B: per-bucket CSR finalize ----------------
// 512 threads (R8 post-mortem: 256-thr/1.5-block-per-CU left the LDS-atomic
// -> scattered-store chains latency-starved; 512thr = 12 waves/CU). The
// 256-bin scan gates on t<256 (wave-uniform). Output packed to 4B/edge:
// (dst<<15) | (fp16(val)>>1).
__global__ __launch_bounds__(512) void k_build(
    const int2* __restrict__ tpairs, const int* __restrict__ G,
    int* __restrict__ row_ptr, unsigned int* __restrict__ pairsu)
{
    __shared__ int hist[256], cursor[256], wsum4[4];
    int b = blockIdx.x, t = threadIdx.x;
    int s_begin = G[b];
    int s_end   = G[b + 1];
    if (t < 256) hist[t] = 0;
    __syncthreads();
    #pragma unroll 4
    for (int pos = s_begin + t; pos < s_end; pos += 512)
        atomicAdd(&hist[(tpairs[pos].x >> 17) & 255], 1);
    __syncthreads();
    // exclusive scan of 256 bins (waves 0-3)
    int lane = t & 63, wid = t >> 6;
    if (t < 256) {
        int v = hist[t], s = v;
        #pragma unroll
        for (int off = 1; off < 64; off <<= 1) {
            int y = __shfl_up(s, off, 64);
            if (lane >= off) s += y;
        }
        if (lane == 63) wsum4[wid] = s;
        __syncthreads();
        if (t == 0) {
            int r = 0;
            #pragma unroll
            for (int k = 0; k < 4; ++k) { int w = wsum4[k]; wsum4[k] = r; r += w; }
        }
        __syncthreads();
        int excl = wsum4[wid] + s - v;
        cursor[t] = excl;
        int node = (b << 8) + t;
        if (node <= N_NODES) row_ptr[node] = s_begin + excl;
    } else {
        __syncthreads();
        __syncthreads();
    }
    __syncthreads();
    #pragma unroll 4
    for (int pos = s_begin + t; pos < s_end; pos += 512) {
        int2 pv = tpairs[pos];
        int k = (pv.x >> 17) & 255;
        int p = atomicAdd(&cursor[k], 1);
        unsigned int dst = (unsigned int)pv.x & 0x1FFFFu;
        unsigned int hb = (unsigned int)__half_as_ushort(
            __float2half_rn(__int_as_float(pv.y)));
        pairsu[s_begin + p] = (dst << 15) | (hb >> 1);
    }
}

// ---------------- aggregation: rep = agg + eps*x ----------------
// 8 edges x 8 lanes/wave, lane loads uint4 (16B) -> 4KB in flight/wave,
// 8 VMEM instrs per 32-edge step; fp16 x everywhere (err ~2^-11).
#define GATHER_BLOCKS 2048

__global__ __launch_bounds__(256) void k_gather(
    const uint4* __restrict__ xh4, const int* __restrict__ row_ptr,
    const unsigned int* __restrict__ pairsu, const float* __restrict__ epsilon,
    float* __restrict__ rep)
{
    int w = (blockIdx.x * 256 + threadIdx.x) >> 6;   // global wave id
    int nw = gridDim.x * 4;                          // 8192
    int lane = threadIdx.x & 63;
    int sub = lane >> 3;                             // edge slot 0..7
    int h8 = lane & 7;                               // 16B chunk idx (8 per row)
    float eps = epsilon[0];

    int r0 = (int)((long long)w * N_NODES / nw);
    int r1 = (int)((long long)(w + 1) * N_NODES / nw);

    for (int row = r0; row < r1; ++row) {
        int start = __builtin_amdgcn_readfirstlane(row_ptr[row]);
        int end   = __builtin_amdgcn_readfirstlane(row_ptr[row + 1]);
        float4 accA = make_float4(0.f, 0.f, 0.f, 0.f);
        float4 accB = make_float4(0.f, 0.f, 0.f, 0.f);
        for (int j = start; j < end; j += 32) {
            unsigned int pk[4]; uint4 a[4];
            #pragma unroll
            for (int u = 0; u < 4; ++u) {
                int e = j + u * 8 + sub;
                pk[u] = (e < end) ? pairsu[e] : 0u;   // 0 -> dst 0, val 0
            }
            #pragma unroll
            for (int u = 0; u < 4; ++u)
                a[u] = xh4[(size_t)(pk[u] >> 15) * 8 + h8];
            #pragma unroll
            for (int u = 0; u < 4; ++u) {
                unsigned short hb = (unsigned short)((pk[u] & 0x7FFFu) << 1);
                float vv = __half2float(__ushort_as_half(hb));
                float2 f0 = __half22float2(*reinterpret_cast<const __half2*>(&a[u].x));
                float2 f1 = __half22float2(*reinterpret_cast<const __half2*>(&a[u].y));
                float2 f2 = __half22float2(*reinterpret_cast<const __half2*>(&a[u].z));
                float2 f3 = __half22float2(*reinterpret_cast<const __half2*>(&a[u].w));
                accA.x += vv * f0.x; accA.y += vv * f0.y;
                accA.z += vv * f1.x; accA.w += vv * f1.y;
                accB.x += vv * f2.x; accB.y += vv * f2.y;
                accB.z += vv * f3.x; accB.w += vv * f3.y;
            }
        }
        // reduce the 8 edge-slots (lane bits 3,4,5)
        #pragma unroll
        for (int off = 8; off <= 32; off <<= 1) {
            accA.x += __shfl_xor(accA.x, off, 64);
            accA.y += __shfl_xor(accA.y, off, 64);
            accA.z += __shfl_xor(accA.z, off, 64);
            accA.w += __shfl_xor(accA.w, off, 64);
            accB.x += __shfl_xor(accB.x, off, 64);
            accB.y += __shfl_xor(accB.y, off, 64);
            accB.z += __shfl_xor(accB.z, off, 64);
            accB.w += __shfl_xor(accB.w, off, 64);
        }
        if (lane < 8) {                              // sub==0, h8==lane
            uint4 xr = xh4[(size_t)row * 8 + lane];
            float2 x0 = __half22float2(*reinterpret_cast<const __half2*>(&xr.x));
            float2 x1 = __half22float2(*reinterpret_cast<const __half2*>(&xr.y));
            float2 x2 = __half22float2(*reinterpret_cast<const __half2*>(&xr.z));
            float2 x3 = __half22float2(*reinterpret_cast<const __half2*>(&xr.w));
            float4* r4 = (float4*)rep;
            r4[(size_t)row * 16 + lane * 2] =
                make_float4(accA.x + eps * x0.x, accA.y + eps * x0.y,
                            accA.z + eps * x1.x, accA.w + eps * x1.y);
            r4[(size_t)row * 16 + lane * 2 + 1] =
                make_float4(accB.x + eps * x2.x, accB.y + eps * x2.y,
                            accB.z + eps * x3.x, accB.w + eps * x3.y);
        }
    }
}

// ---------------- out = rep @ W + bias ----------------
#define GEMM_TM 64
__global__ __launch_bounds__(256) void k_gemm(
    const float* __restrict__ rep, const float* __restrict__ weight,
    const float* __restrict__ bias, float* __restrict__ out)
{
    __shared__ float rep_s[GEMM_TM * 68];
    __shared__ float Ws[D * D];
    int t = threadIdx.x;
    {
        const float4* w4 = (const float4*)weight;
        float4* s4 = (float4*)Ws;
        #pragma unroll
        for (int i = 0; i < (D * D / 4) / 256; ++i)
            s4[t + i * 256] = w4[t + i * 256];
    }
    int row0 = blockIdx.x * GEMM_TM;
    {
        const float4* r4 = (const float4*)rep;
        #pragma unroll
        for (int i = 0; i < 4; ++i) {
            int f = t + i * 256;
            int rr = f >> 4, kk4 = f & 15;
            float4 v = (row0 + rr < N_NODES) ? r4[(size_t)(row0 + rr) * 16 + kk4]
                                             : make_float4(0.f, 0.f, 0.f, 0.f);
            rep_s[rr * 68 + kk4 * 4 + 0] = v.x;
            rep_s[rr * 68 + kk4 * 4 + 1] = v.y;
            rep_s[rr * 68 + kk4 * 4 + 2] = v.z;
            rep_s[rr * 68 + kk4 * 4 + 3] = v.w;
        }
    }
    __syncthreads();

    int tx = t & 15, ty = t >> 4;
    float4 b4 = ((const float4*)bias)[tx];
    float acc[4][4];
    #pragma unroll
    for (int i = 0; i < 4; ++i) {
        acc[i][0] = b4.x; acc[i][1] = b4.y; acc[i][2] = b4.z; acc[i][3] = b4.w;
    }
    #pragma unroll 4
    for (int k4 = 0; k4 < 16; ++k4) {
        float4 rv[4];
        #pragma unroll
        for (int i = 0; i < 4; ++i)
            rv[i] = *(const float4*)&rep_s[(ty * 4 + i) * 68 + k4 * 4];
        #pragma unroll
        for (int kk = 0; kk < 4; ++kk) {
            float4 wv = *(const float4*)&Ws[(k4 * 4 + kk) * D + tx * 4];
            #pragma unroll
            for (int i = 0; i < 4; ++i) {
                float r = ((const float*)&rv[i])[kk];
                acc[i][0] += r * wv.x;
                acc[i][1] += r * wv.y;
                acc[i][2] += r * wv.z;
                acc[i][3] += r * wv.w;
            }
        }
    }
    #pragma unroll
    for (int i = 0; i < 4; ++i) {
        int row = row0 + ty * 4 + i;
        if (row < N_NODES)
            *(float4*)&out[(size_t)row * D + tx * 4] =
                make_float4(acc[i][0], acc[i][1], acc[i][2], acc[i][3]);
    }
}

extern "C" void kernel_launch(void* const* d_in, const int* in_sizes, int n_in,
                              void* d_out, int out_size, void* d_ws, size_t ws_size,
                              hipStream_t stream) {
    const float* x    = (const float*)d_in[0];
    const int*   esrc = (const int*)  d_in[1];
    const int*   edst = (const int*)  d_in[2];
    const float* ev   = (const float*)d_in[3];
    const float* w    = (const float*)d_in[4];
    const float* eps  = (const float*)d_in[5];
    const float* bias = (const float*)d_in[6];

    float* out = (float*)d_out;
    float* rep = out + (size_t)N_NODES * D;

    int* ws       = (int*)d_ws;
    int* ghist    = ws + WS_GHIST;
    int* G        = ws + WS_G;
    int* row_ptr  = ws + WS_ROWPTR;
    unsigned int* pairsu = (unsigned int*)(ws + WS_PAIRSU);
    uint2* xh2    = (uint2*)(ws + WS_XH);
    uint4* xh4    = (uint4*)(ws + WS_XH);
    int2* tpairs  = (int2*)rep;   // consumed by k_build before k_gather writes rep

    k_hist_cvt<<<BLKA, 512, 0, stream>>>(esrc, x, ghist, xh2);
    k_scatter<<<BLKA, 512, 0, stream>>>(esrc, edst, ev, ghist, G, tpairs);
    k_build<<<NB, 512, 0, stream>>>(tpairs, G, row_ptr, pairsu);
    k_gather<<<GATHER_BLOCKS, 256, 0, stream>>>(xh4, row_ptr, pairsu, eps, rep);
    k_gemm<<<(N_NODES + GEMM_TM - 1) / GEMM_TM, 256, 0, stream>>>(rep, w, bias, out);
}